// Round 4
// baseline (15546.460 us; speedup 1.0000x reference)
//
#include <hip/hip_runtime.h>
#include <hip/hip_bf16.h>

#define B_   64
#define T_   2048
#define F_   256
#define H_   512
#define NWG  64

typedef __attribute__((ext_vector_type(8))) short bfrag;   // 8 bf16 = 4 VGPR (MFMA A/B operand)
typedef __attribute__((ext_vector_type(4))) int   int4v;   // 16B payload
typedef __attribute__((ext_vector_type(4))) float f32x4;   // MFMA C/D
typedef __attribute__((ext_vector_type(4))) float float4_t;

__device__ __forceinline__ float fsig(float x)  { return 1.0f / (1.0f + __expf(-x)); }
__device__ __forceinline__ float ftanh(float x) { return 2.0f / (1.0f + __expf(-2.0f * x)) - 1.0f; }

__device__ __forceinline__ short f2bf(float f) {
  __hip_bfloat16 h = __float2bfloat16(f);
  return __builtin_bit_cast(short, h);
}

// ---- coherence-point (sc0 sc1 = bypass L1+L2, serviced at MALL) asm ops ----
__device__ __forceinline__ int4v gload16_cc(const void* p) {
  int4v r;
  asm volatile("global_load_dwordx4 %0, %1, off sc0 sc1" : "=v"(r) : "v"(p));
  return r;
}
__device__ __forceinline__ int gload_flag(const void* p) {
  int r;
  asm volatile("global_load_dword %0, %1, off sc0 sc1\n\ts_waitcnt vmcnt(0)"
               : "=v"(r) : "v"(p) : "memory");
  return r;
}
__device__ __forceinline__ void gstore4_cc(void* p, unsigned int d) {
  asm volatile("global_store_dword %0, %1, off sc0 sc1" :: "v"(p), "v"(d));
}
__device__ __forceinline__ void gstore16_cc(void* p, int4v d) {
  asm volatile("global_store_dwordx4 %0, %1, off sc0 sc1" :: "v"(p), "v"(d));
}
__device__ __forceinline__ void vm_drain() {
  asm volatile("s_waitcnt vmcnt(0)" ::: "memory");
  __builtin_amdgcn_sched_barrier(0);   // rule #18
}
__device__ __forceinline__ void lds_drain() {
  asm volatile("s_waitcnt lgkmcnt(0)" ::: "memory");
  __builtin_amdgcn_sched_barrier(0);   // rule #18
}

// ---------------- init: zero flags, h0 = bf16(z) ----------------
__global__ void lstm_init(const float* __restrict__ z, __hip_bfloat16* __restrict__ hb0,
                          int* __restrict__ wgdone) {
  int i = blockIdx.x * blockDim.x + threadIdx.x;
  if (i < NWG) wgdone[i] = 0;
  for (int idx = i; idx < B_ * H_; idx += gridDim.x * blockDim.x)
    hb0[idx] = __float2bfloat16(z[idx]);
}

// ---------------- persistent LSTM ----------------
// WG g owns: gate rows {q*512 + g*8 + j} -> h cols [g*8,g*8+8); out cols [g*4,g*4+4).
// Wave w owns batch rows [16w,16w+16).
// h loads: wave-coalesced 1KB UC loads -> LDS (XOR-swizzled) -> b128 fragment reads.
// h stores: row-gathered 16B UC stores. Flags: UC dword. No cache-maint fences.
__global__ void __launch_bounds__(256, 1)
lstm_persist(const float* __restrict__ x,
             const float* __restrict__ Wih,  const float* __restrict__ Whh,
             const float* __restrict__ bih,  const float* __restrict__ bhh,
             const float* __restrict__ Wlin, const float* __restrict__ blin,
             float* __restrict__ out,
             __hip_bfloat16* __restrict__ hb0, __hip_bfloat16* __restrict__ hb1,
             int* __restrict__ wgdone)
{
  __shared__ int4v sm[4096];           // 64KB: 16KB per wave, no cross-wave sharing

  const int g   = blockIdx.x;
  const int tid = threadIdx.x;
  const int wv  = tid >> 6;
  const int l   = tid & 63;
  const int l16 = l & 15;
  const int q   = l >> 4;              // quarter-wave 0..3
  const int lk  = q << 3;              // k sub-offset: 0,8,16,24

  // ---- persistent weight fragments (bf16) ----
  bfrag BW[2][24];
  #pragma unroll
  for (int nt = 0; nt < 2; ++nt) {
    const int n   = nt * 16 + l16;
    const int row = (n >> 3) * H_ + g * 8 + (n & 7);
    #pragma unroll
    for (int kt = 0; kt < 24; ++kt) {
      const float* src = (kt < 8) ? (Wih + (size_t)row * F_ + kt * 32 + lk)
                                  : (Whh + (size_t)row * H_ + (kt - 8) * 32 + lk);
      bfrag w;
      #pragma unroll
      for (int e = 0; e < 8; ++e) w[e] = f2bf(src[e]);
      BW[nt][kt] = w;
    }
  }
  bfrag BL[16];
  {
    const bool v  = (l16 < 4);
    const int col = g * 4 + (l16 & 3);
    #pragma unroll
    for (int kt = 0; kt < 16; ++kt) {
      bfrag w;
      #pragma unroll
      for (int e = 0; e < 8; ++e)
        w[e] = v ? f2bf(Wlin[(size_t)col * H_ + kt * 32 + lk + e]) : (short)0;
      BL[kt] = w;
    }
  }
  float bs0 = 0.f, bs1 = 0.f, bs2 = 0.f, bs3 = 0.f, blc = 0.f;
  if (l16 < 8) {
    const int c0 = g * 8 + l16;
    bs0 = bih[c0]          + bhh[c0];
    bs1 = bih[H_ + c0]     + bhh[H_ + c0];
    bs2 = bih[2 * H_ + c0] + bhh[2 * H_ + c0];
    bs3 = bih[3 * H_ + c0] + bhh[3 * H_ + c0];
  }
  if (l16 < 4) blc = blin[g * 4 + l16];

  float c4[4] = {0.f, 0.f, 0.f, 0.f};

  const int am     = wv * 16 + l16;              // A-operand batch row
  const int dmBase = wv * 16 + (q << 2);         // D row base (+reg)

  // LDS fragment index for k-tile kt (this wave's block); row = l16
  auto fragIdx = [&](int kt) {
    return wv * 1024 + l16 * 64 + ((kt * 4 + q) ^ (l16 & 7));
  };

  auto xpart = [&](int t, f32x4& a0, f32x4& a1) {
    const float* xrow = x + ((size_t)am * T_ + t) * F_ + lk;
    #pragma unroll
    for (int kt = 0; kt < 8; ++kt) {
      float4_t xa = *(const float4_t*)(xrow + kt * 32);
      float4_t xb = *(const float4_t*)(xrow + kt * 32 + 4);
      bfrag a;
      #pragma unroll
      for (int e = 0; e < 4; ++e) { a[e] = f2bf(xa[e]); a[4 + e] = f2bf(xb[e]); }
      a0 = __builtin_amdgcn_mfma_f32_16x16x32_bf16(a, BW[0][kt], a0, 0, 0, 0);
      a1 = __builtin_amdgcn_mfma_f32_16x16x32_bf16(a, BW[1][kt], a1, 0, 0, 0);
    }
  };

  f32x4 xp0 = {0.f, 0.f, 0.f, 0.f}, xp1 = {0.f, 0.f, 0.f, 0.f};
  xpart(0, xp0, xp1);

  for (int t = 0; t < T_; ++t) {
    // ---- wait for h_t ----
    if (t > 0) {
      while (true) {
        int v = gload_flag(&wgdone[l]);
        if (__all(v >= t)) break;
        __builtin_amdgcn_s_sleep(1);
      }
      __builtin_amdgcn_sched_barrier(0);
    }

    const __hip_bfloat16* hcur = (t & 1) ? hb1 : hb0;
    __hip_bfloat16*       hnxt = (t & 1) ? hb0 : hb1;

    // ---- h load: 16 wave-coalesced 1KB UC loads (rows wv*16..wv*16+15) ----
    int4v hv[16];
    const char* hbase = (const char*)hcur + (size_t)(wv * 16) * (H_ * 2) + l * 16;
    #pragma unroll
    for (int j = 0; j < 16; ++j)
      hv[j] = gload16_cc(hbase + (size_t)j * (H_ * 2));
    vm_drain();

    // ---- stage to LDS (XOR-swizzled), own-wave region, no barrier ----
    #pragma unroll
    for (int j = 0; j < 16; ++j)
      sm[wv * 1024 + j * 64 + (l ^ (j & 7))] = hv[j];
    lds_drain();

    // ---- gates: h part (K 256..767) on precomputed x part ----
    f32x4 acc0 = xp0, acc1 = xp1;
    #pragma unroll
    for (int kt = 0; kt < 16; ++kt) {
      bfrag ha = __builtin_bit_cast(bfrag, sm[fragIdx(kt)]);
      acc0 = __builtin_amdgcn_mfma_f32_16x16x32_bf16(ha, BW[0][8 + kt], acc0, 0, 0, 0);
      acc1 = __builtin_amdgcn_mfma_f32_16x16x32_bf16(ha, BW[1][8 + kt], acc1, 0, 0, 0);
    }

    // ---- activations, state, row-gathered 16B h stores ----
    #pragma unroll
    for (int r = 0; r < 4; ++r) {
      float fvx = __shfl_xor(acc0[r], 8);
      float ovx = __shfl_xor(acc1[r], 8);
      float hn = 0.f;
      if (l16 < 8) {
        float iv = fsig(acc0[r] + bs0);
        float fv = fsig(fvx + bs1);
        float gv = ftanh(acc1[r] + bs2);
        float ov = fsig(ovx + bs3);
        float cn = fv * c4[r] + iv * gv;
        c4[r] = cn;
        hn = ov * ftanh(cn);
      }
      int hb16 = (int)(unsigned short)f2bf(hn);
      int pu   = __shfl_xor(hb16, 1);
      unsigned int packed = ((unsigned)hb16 & 0xffffu) | ((unsigned)pu << 16);
      // gather 4 packed dwords (cols g*8..g*8+7) of row dmBase+r into lane l16==0
      const int base = l & 48;
      unsigned int p0 = __shfl(packed, base + 0);
      unsigned int p1 = __shfl(packed, base + 2);
      unsigned int p2 = __shfl(packed, base + 4);
      unsigned int p3 = __shfl(packed, base + 6);
      if (l16 == 0) {
        int4v v4 = {(int)p0, (int)p1, (int)p2, (int)p3};
        gstore16_cc((char*)hnxt + (size_t)(dmBase + r) * (H_ * 2) + g * 16, v4);
      }
    }

    vm_drain();        // h stores completed at coherence point
    __syncthreads();
    if (tid == 0)
      gstore4_cc(&wgdone[g], (unsigned int)(t + 1));

    // ---- shadow: out[t-1] GEMM + store, next x part ----
    if (t > 0) {
      f32x4 oacc = {blc, blc, blc, blc};
      #pragma unroll
      for (int kt = 0; kt < 16; ++kt) {
        bfrag ha = __builtin_bit_cast(bfrag, sm[fragIdx(kt)]);
        oacc = __builtin_amdgcn_mfma_f32_16x16x32_bf16(ha, BL[kt], oacc, 0, 0, 0);
      }
      if (l16 < 4) {
        #pragma unroll
        for (int r = 0; r < 4; ++r)
          out[(size_t)(dmBase + r) * T_ * F_ + (size_t)(t - 1) * F_ + g * 4 + l16] = oacc[r];
      }
    }
    xp0 = (f32x4){0.f, 0.f, 0.f, 0.f};
    xp1 = (f32x4){0.f, 0.f, 0.f, 0.f};
    if (t + 1 < T_) xpart(t + 1, xp0, xp1);
  }

  // ---- tail: out[:, T-1, :] from h_T (in hb0, T even) ----
  {
    while (true) {
      int v = gload_flag(&wgdone[l]);
      if (__all(v >= T_)) break;
      __builtin_amdgcn_s_sleep(1);
    }
    __builtin_amdgcn_sched_barrier(0);

    int4v hv[16];
    const char* hbase = (const char*)hb0 + (size_t)(wv * 16) * (H_ * 2) + l * 16;
    #pragma unroll
    for (int j = 0; j < 16; ++j)
      hv[j] = gload16_cc(hbase + (size_t)j * (H_ * 2));
    vm_drain();
    #pragma unroll
    for (int j = 0; j < 16; ++j)
      sm[wv * 1024 + j * 64 + (l ^ (j & 7))] = hv[j];
    lds_drain();

    f32x4 oacc = {blc, blc, blc, blc};
    #pragma unroll
    for (int kt = 0; kt < 16; ++kt) {
      bfrag ha = __builtin_bit_cast(bfrag, sm[fragIdx(kt)]);
      oacc = __builtin_amdgcn_mfma_f32_16x16x32_bf16(ha, BL[kt], oacc, 0, 0, 0);
    }
    if (l16 < 4) {
      #pragma unroll
      for (int r = 0; r < 4; ++r)
        out[(size_t)(dmBase + r) * T_ * F_ + (size_t)(T_ - 1) * F_ + g * 4 + l16] = oacc[r];
    }
  }
}

extern "C" void kernel_launch(void* const* d_in, const int* in_sizes, int n_in,
                              void* d_out, int out_size, void* d_ws, size_t ws_size,
                              hipStream_t stream) {
  const float* z    = (const float*)d_in[0];
  const float* x    = (const float*)d_in[1];
  const float* Wih  = (const float*)d_in[2];
  const float* Whh  = (const float*)d_in[3];
  const float* bih  = (const float*)d_in[4];
  const float* bhh  = (const float*)d_in[5];
  const float* Wlin = (const float*)d_in[6];
  const float* blin = (const float*)d_in[7];
  float* out = (float*)d_out;

  __hip_bfloat16* hb0 = (__hip_bfloat16*)d_ws;
  __hip_bfloat16* hb1 = hb0 + B_ * H_;
  int* wgdone = (int*)((char*)d_ws + (size_t)2 * B_ * H_ * sizeof(__hip_bfloat16));

  lstm_init<<<64, 256, 0, stream>>>(z, hb0, wgdone);
  lstm_persist<<<NWG, 256, 0, stream>>>(x, Wih, Whh, bih, bhh, Wlin, blin, out,
                                        hb0, hb1, wgdone);
}

// Round 5
// 14185.658 us; speedup vs baseline: 1.0959x; 1.0959x over previous
//
#include <hip/hip_runtime.h>
#include <hip/hip_bf16.h>

#define B_   64
#define T_   2048
#define F_   256
#define H_   512
#define GB   4                    // batch groups (16 rows each)
#define GG   8                    // gate-split WGs per group
#define NWG  (GB*GG)              // 32
#define PKTS_PER_GROUP 4096       // 16 rows * 256 col-pairs
#define SLOTS 4

typedef __attribute__((ext_vector_type(8))) short bfrag;   // 8 bf16 (MFMA A/B)
typedef __attribute__((ext_vector_type(4))) int   int4v;
typedef __attribute__((ext_vector_type(2))) int   int2v;   // 8B packet {payload, tag}
typedef __attribute__((ext_vector_type(4))) float f32x4;
typedef __attribute__((ext_vector_type(4))) float float4_t;

__device__ __forceinline__ float fsig(float x)  { return 1.0f / (1.0f + __expf(-x)); }
__device__ __forceinline__ float ftanh(float x) { return 2.0f / (1.0f + __expf(-2.0f * x)) - 1.0f; }
__device__ __forceinline__ short f2bf(float f) {
  __hip_bfloat16 h = __float2bfloat16(f);
  return __builtin_bit_cast(short, h);
}

// coherence-point (sc0 sc1) ops — bypass L1+L2, serviced at MALL
__device__ __forceinline__ int2v gload8_cc(const void* p) {
  int2v r;
  asm volatile("global_load_dwordx2 %0, %1, off sc0 sc1" : "=v"(r) : "v"(p));
  return r;
}
__device__ __forceinline__ void gstore8_cc(void* p, int2v d) {
  asm volatile("global_store_dwordx2 %0, %1, off sc0 sc1" :: "v"(p), "v"(d));
}
__device__ __forceinline__ void vm_drain() {
  asm volatile("s_waitcnt vmcnt(0)" ::: "memory");
  __builtin_amdgcn_sched_barrier(0);   // rule #18
}

// ---------------- init: slot-0 packets = h_0 = bf16(z), tag 0 ----------------
__global__ void lstm_init(const float* __restrict__ z, unsigned long long* __restrict__ pkt0) {
  int i = blockIdx.x * blockDim.x + threadIdx.x;     // 0..16383
  int g  = i >> 12;            // group
  int p  = i & 4095;
  int j  = p >> 8;             // row within group
  int pr = p & 255;            // col pair
  int row = 16 * g + j;
  unsigned int lo = (unsigned)(unsigned short)f2bf(z[(size_t)row * H_ + 2 * pr])
                  | ((unsigned)(unsigned short)f2bf(z[(size_t)row * H_ + 2 * pr + 1]) << 16);
  pkt0[i] = (unsigned long long)lo;                  // tag (high dword) = 0
}

// ---------------- persistent LSTM, batch-grouped ----------------
// WG(b,k): batch rows [16b,16b+16), h-cols [64k,64k+64), out-cols [32k,32k+32).
// Wave wv owns gate cols 16wv+l16 (all 4 gates). Packet protocol:
// pkt[slot][group][row m][pair] = {2 bf16, tag}; tag==t <=> h_t valid.
// Producers fire-and-forget; consumer poll's vmcnt(0) bounds in-flight stores
// so 4-slot rotation at skew<=1 is race-free. MFMA layouts as rounds 1-4.
__global__ void __launch_bounds__(256, 1)
lstm_persist(const float* __restrict__ x,
             const float* __restrict__ Wih,  const float* __restrict__ Whh,
             const float* __restrict__ bih,  const float* __restrict__ bhh,
             const float* __restrict__ Wlin, const float* __restrict__ blin,
             float* __restrict__ out, int2v* __restrict__ pkt)
{
  __shared__ char smem[49152];   // [0,16K): h-tile [16][512]bf16 swz; [16K,48K): W_lin slice

  const int wg  = blockIdx.x;
  const int b   = wg >> 3;
  const int k   = wg & 7;
  const int tid = threadIdx.x;
  const int wv  = tid >> 6;
  const int l   = tid & 63;
  const int l16 = l & 15;
  const int qq  = l >> 4;
  const int swz = (l16 & 7) << 4;
  const int m4  = qq << 2;                 // D row base (+reg)

  // ---- stage W_lin slice (cols 32k..32k+32, K=512) to LDS, swizzled ----
  {
    const int oc = tid >> 3;               // 0..31
    const float* src = Wlin + (size_t)(32 * k + oc) * H_ + (tid & 7) * 64;
    char* dst = smem + 16384 + oc * 1024;
    #pragma unroll
    for (int i = 0; i < 8; ++i) {
      bfrag tmp;
      #pragma unroll
      for (int e = 0; e < 8; ++e) tmp[e] = f2bf(src[i * 8 + e]);
      *(int4v*)(dst + ((((tid & 7) * 128) + i * 16) ^ ((oc & 7) << 4))) =
          __builtin_bit_cast(int4v, tmp);
    }
  }

  // ---- persistent weight fragments in VGPR ----
  bfrag WH[4][16];   // W_hh: gate q, k-tile kt
  bfrag WI[4][8];    // W_ih
  float bs[4];
  #pragma unroll
  for (int q = 0; q < 4; ++q) {
    const int grow = q * H_ + k * 64 + wv * 16 + l16;   // this lane's gate row
    #pragma unroll
    for (int kt = 0; kt < 16; ++kt) {
      const float* s = Whh + (size_t)grow * H_ + kt * 32 + qq * 8;
      bfrag w;
      #pragma unroll
      for (int e = 0; e < 8; ++e) w[e] = f2bf(s[e]);
      WH[q][kt] = w;
    }
    #pragma unroll
    for (int kt = 0; kt < 8; ++kt) {
      const float* s = Wih + (size_t)grow * F_ + kt * 32 + qq * 8;
      bfrag w;
      #pragma unroll
      for (int e = 0; e < 8; ++e) w[e] = f2bf(s[e]);
      WI[q][kt] = w;
    }
    bs[q] = bih[grow] + bhh[grow];
  }
  const float blc = (wv < 2) ? blin[32 * k + 16 * wv + l16] : 0.f;

  float c4[4] = {0.f, 0.f, 0.f, 0.f};
  __syncthreads();   // W_lin staged

  for (int t = 0; t < T_; ++t) {
    // ---- A: x-part of gates (h-independent shadow work, absorbs group skew) ----
    f32x4 acc[4] = {{0,0,0,0},{0,0,0,0},{0,0,0,0},{0,0,0,0}};
    {
      const float* xr = x + ((size_t)(16 * b + l16) * T_ + t) * F_ + qq * 8;
      #pragma unroll
      for (int kt = 0; kt < 8; ++kt) {
        float4_t xa = *(const float4_t*)(xr + kt * 32);
        float4_t xb = *(const float4_t*)(xr + kt * 32 + 4);
        bfrag a;
        #pragma unroll
        for (int e = 0; e < 4; ++e) { a[e] = f2bf(xa[e]); a[4 + e] = f2bf(xb[e]); }
        #pragma unroll
        for (int q = 0; q < 4; ++q)
          acc[q] = __builtin_amdgcn_mfma_f32_16x16x32_bf16(a, WI[q][kt], acc[q], 0, 0, 0);
      }
    }

    // ---- B: poll h_t packets (slot t&3); lane owns (row j, pair tid), j=0..15 ----
    const int2v* pp = pkt + (size_t)((t & 3) * GB + b) * PKTS_PER_GROUP + tid;
    int2v pv[16];
    while (true) {
      #pragma unroll
      for (int j = 0; j < 16; ++j) pv[j] = gload8_cc(pp + j * 256);
      vm_drain();                            // also bounds in-flight pkt stores
      bool ok = true;
      #pragma unroll
      for (int j = 0; j < 16; ++j) ok &= (pv[j].y == t);
      if (__all(ok)) break;
      __builtin_amdgcn_s_sleep(2);
    }
    __syncthreads();    // all waves done with prior iter's LDS reads

    // ---- C: build h-tile in LDS (swizzled) ----
    #pragma unroll
    for (int j = 0; j < 16; ++j)
      *(int*)(smem + j * 1024 + ((tid * 4) ^ ((j & 7) << 4))) = pv[j].x;
    __syncthreads();

    // ---- D: gates h-part + fused out[t-1] (waves 0,1 own the 2 out n-tiles) ----
    f32x4 oacc = {blc, blc, blc, blc};
    #pragma unroll
    for (int kt = 0; kt < 16; ++kt) {
      bfrag a = *(const bfrag*)(smem + l16 * 1024 + ((kt * 64 + qq * 16) ^ swz));
      #pragma unroll
      for (int q = 0; q < 4; ++q)
        acc[q] = __builtin_amdgcn_mfma_f32_16x16x32_bf16(a, WH[q][kt], acc[q], 0, 0, 0);
      if (wv < 2) {
        bfrag wl = *(const bfrag*)(smem + 16384 + (16 * wv + l16) * 1024 +
                                   ((kt * 64 + qq * 16) ^ swz));
        oacc = __builtin_amdgcn_mfma_f32_16x16x32_bf16(a, wl, oacc, 0, 0, 0);
      }
    }

    // ---- E: activations, state, tagged pkt stores (fire & forget) ----
    int2v* ps = pkt + (size_t)(((t + 1) & 3) * GB + b) * PKTS_PER_GROUP;
    #pragma unroll
    for (int r = 0; r < 4; ++r) {
      float iv = fsig(acc[0][r] + bs[0]);
      float fv = fsig(acc[1][r] + bs[1]);
      float gv = ftanh(acc[2][r] + bs[2]);
      float ov = fsig(acc[3][r] + bs[3]);
      float cn = fv * c4[r] + iv * gv;
      c4[r] = cn;
      float hn = ov * ftanh(cn);
      int hb = (int)(unsigned short)f2bf(hn);
      int pu = __shfl_xor(hb, 1);
      if ((l16 & 1) == 0) {
        int2v pk;
        pk.x = (hb & 0xffff) | (pu << 16);
        pk.y = t + 1;
        gstore8_cc(ps + (m4 + r) * 256 + (32 * k + 8 * wv + (l16 >> 1)), pk);
      }
    }

    // ---- F: out[t-1] store (cached) ----
    if (t > 0 && wv < 2) {
      #pragma unroll
      for (int r = 0; r < 4; ++r)
        out[(size_t)(16 * b + m4 + r) * T_ * F_ + (size_t)(t - 1) * F_ +
            32 * k + 16 * wv + l16] = oacc[r];
    }
  }

  // ---- tail: out[T-1] from h_T (slot T_&3 == 0, tag T_) ----
  {
    const int2v* pp = pkt + (size_t)((T_ & 3) * GB + b) * PKTS_PER_GROUP + tid;
    int2v pv[16];
    while (true) {
      #pragma unroll
      for (int j = 0; j < 16; ++j) pv[j] = gload8_cc(pp + j * 256);
      vm_drain();
      bool ok = true;
      #pragma unroll
      for (int j = 0; j < 16; ++j) ok &= (pv[j].y == T_);
      if (__all(ok)) break;
      __builtin_amdgcn_s_sleep(2);
    }
    __syncthreads();
    #pragma unroll
    for (int j = 0; j < 16; ++j)
      *(int*)(smem + j * 1024 + ((tid * 4) ^ ((j & 7) << 4))) = pv[j].x;
    __syncthreads();

    if (wv < 2) {
      f32x4 oacc = {blc, blc, blc, blc};
      #pragma unroll
      for (int kt = 0; kt < 16; ++kt) {
        bfrag a  = *(const bfrag*)(smem + l16 * 1024 + ((kt * 64 + qq * 16) ^ swz));
        bfrag wl = *(const bfrag*)(smem + 16384 + (16 * wv + l16) * 1024 +
                                   ((kt * 64 + qq * 16) ^ swz));
        oacc = __builtin_amdgcn_mfma_f32_16x16x32_bf16(a, wl, oacc, 0, 0, 0);
      }
      #pragma unroll
      for (int r = 0; r < 4; ++r)
        out[(size_t)(16 * b + m4 + r) * T_ * F_ + (size_t)(T_ - 1) * F_ +
            32 * k + 16 * wv + l16] = oacc[r];
    }
  }
}

extern "C" void kernel_launch(void* const* d_in, const int* in_sizes, int n_in,
                              void* d_out, int out_size, void* d_ws, size_t ws_size,
                              hipStream_t stream) {
  const float* z    = (const float*)d_in[0];
  const float* x    = (const float*)d_in[1];
  const float* Wih  = (const float*)d_in[2];
  const float* Whh  = (const float*)d_in[3];
  const float* bih  = (const float*)d_in[4];
  const float* bhh  = (const float*)d_in[5];
  const float* Wlin = (const float*)d_in[6];
  const float* blin = (const float*)d_in[7];
  float* out = (float*)d_out;

  int2v* pkt = (int2v*)d_ws;   // SLOTS*GB*4096 pkts * 8B = 512 KB

  lstm_init<<<64, 256, 0, stream>>>(z, (unsigned long long*)d_ws);
  lstm_persist<<<NWG, 256, 0, stream>>>(x, Wih, Whh, bih, bhh, Wlin, blin, out, pkt);
}